// Round 12
// baseline (458.297 us; speedup 1.0000x reference)
//
#include <hip/hip_runtime.h>
#include <hip/hip_fp16.h>

typedef unsigned short u16;
typedef _Float16 half8 __attribute__((ext_vector_type(8)));
typedef float floatx4 __attribute__((ext_vector_type(4)));

#define C_DIM 256
#define P_DIM 2048
#define L_DIM 1024
#define N_DIM 16
#define KEEP 102
#define KPAD 104
#define QTR_PIX 4096    // pixels per quarter-pass
#define SCALE 256.0f    // 2^8 input pre-scale; both operands scaled -> acc at 2^16.
                        // Downstream is scale-invariant (topk order + w/Sum(w)).

__device__ __forceinline__ void st8(u16* dst, const u16* s) {
  uint4 u;
  u.x = (unsigned)s[0] | ((unsigned)s[1] << 16);
  u.y = (unsigned)s[2] | ((unsigned)s[3] << 16);
  u.z = (unsigned)s[4] | ((unsigned)s[5] << 16);
  u.w = (unsigned)s[6] | ((unsigned)s[7] << 16);
  *(uint4*)dst = u;
}

// fp32 -> fp16 with flush-to-zero of subnormal results (MFMA denormal guard).
__device__ __forceinline__ u16 f2h_ftz(float v) {
  if (fabsf(v) < 6.103515625e-5f) return 0;
  return __half_as_ushort(__float2half(v));
}

// async global->LDS, 16B per lane. LDS dest is wave-uniform base + lane*16.
__device__ __forceinline__ void gl_lds16(const u16* g, u16* l) {
  __builtin_amdgcn_global_load_lds(
      (const __attribute__((address_space(1))) unsigned int*)g,
      (__attribute__((address_space(3))) unsigned int*)l, 16, 0, 0);
}

// shared-memory overlay: M role needs 32 KB staging, S role ~15 KB
union SMem {
  u16 sB[2][2][8][512];                               // 32768 B
  struct {
    float tbuf[8][260];                               // 8320 B
    int2  kpw[8][KPAD];                               // 6656 B (byte-off, weight)
  } sel;
};

// ---- dataflow flags (in d_ws, zeroed by k_pinv each launch) ----
// pack_cnt[q][g] -> 8 when unit g's B rows for quarter q are packed
// mf_cnt[q][g]   -> 16 when unit g's sbuf region for quarter q is written
// rd_cnt[q][g]   -> 16 when unit g's select for quarter q is done (slot free)
#define F_PACK 0
#define F_MF   128
#define F_RD   256
#define F_TOTAL 384

// relaxed poll (no per-poll cache inv), single acquire after satisfied
__device__ __forceinline__ void wait_flag(int* f, int target) {
  if (threadIdx.x == 0) {
    while (__hip_atomic_load(f, __ATOMIC_RELAXED, __HIP_MEMORY_SCOPE_AGENT) < target)
      __builtin_amdgcn_s_sleep(8);
    (void)__hip_atomic_load(f, __ATOMIC_ACQUIRE, __HIP_MEMORY_SCOPE_AGENT);
  }
  __syncthreads();
}
// release signal: caller must have passed a __syncthreads() after its writes
__device__ __forceinline__ void signal_flag(int* f) {
  if (threadIdx.x == 0)
    __hip_atomic_fetch_add(f, 1, __ATOMIC_RELEASE, __HIP_MEMORY_SCOPE_AGENT);
}

// ---------------- kernel 1a: pinv[p] = 1/||pool_p|| + flag zeroing ----------
__global__ __launch_bounds__(256) void k_pinv(const float* __restrict__ pool,
                                              float* __restrict__ pinv,
                                              int* __restrict__ flags) {
  int p = blockIdx.x * 256 + threadIdx.x;
  if (p < F_TOTAL) flags[p] = 0;
  const float4* row = (const float4*)(pool + (size_t)p * C_DIM);
  float s = 0.f;
#pragma unroll
  for (int i = 0; i < C_DIM / 4; ++i) {
    float4 v = row[i];
    s += v.x * v.x + v.y * v.y + v.z * v.z + v.w * v.w;
  }
  pinv[p] = 1.0f / sqrtf(s);
}

// ------- packpool role: pool*pinv*2^8 into MFMA-A frag order, fp16 hi/lo,
//         plus raw fp16 pool copy for the recon gather. 128 blocks x 512 thr. --
// frag element (pm, ks, lane, j): p = pm*16 + (lane&15), c = ks*32 + (lane>>4)*8 + j
__device__ __forceinline__ void packpool_body(int b,
                                              const float* __restrict__ pool,
                                              const float* __restrict__ pinv,
                                              u16* __restrict__ ah,
                                              u16* __restrict__ al,
                                              u16* __restrict__ ph) {
  int tid = b * 512 + threadIdx.x;              // 65536 = 128*8*64
  int lane = tid & 63;
  int ks = (tid >> 6) & 7;
  int pm = tid >> 9;
  int p = pm * 16 + (lane & 15);
  int c0 = ks * 32 + ((lane >> 4) << 3);
  float sc = pinv[p] * SCALE;
  const float* src = pool + (size_t)p * C_DIM + c0;
  u16 h8[8], l8[8], p8[8];
#pragma unroll
  for (int j = 0; j < 8; ++j) {
    float raw = src[j];
    p8[j] = __half_as_ushort(__float2half(raw));
    float v = raw * sc;
    u16 h = f2h_ftz(v);
    float r = v - __half2float(__ushort_as_half(h));  // exact (Sterbenz range)
    h8[j] = h;
    l8[j] = f2h_ftz(r);
  }
  size_t o = (size_t)tid * 8;
  st8(ah + o, h8); st8(al + o, l8);
  st8(ph + (size_t)p * C_DIM + c0, p8);
}

// ------- packx role: x*2^8 into MFMA-B frag order, fp16 hi/lo split ---------
// Packs one pn (16-pixel group) with 512 threads; pn = pq*256 + pb.
// frag element (pn, ks, lane, j): pix = pn*16 + (lane&15), c = ks*32 + (lane>>4)*8 + j
__device__ __forceinline__ void packx_body(int pb, int pq,
                                           const float* __restrict__ x,
                                           u16* __restrict__ xh,
                                           u16* __restrict__ xl) {
  int t = threadIdx.x;
  int lane = t & 63;
  int ks = (t >> 6) & 7;
  int pn = pq * 256 + pb;
  int pix = pn * 16 + (lane & 15);
  int n = pix >> 10, l = pix & 1023;
  int c0 = ks * 32 + ((lane >> 4) << 3);
  const float* src = x + ((size_t)(n * C_DIM + c0)) * L_DIM + l;
  u16 h8[8], l8[8];
#pragma unroll
  for (int j = 0; j < 8; ++j) {
    float v = src[(size_t)j * L_DIM] * SCALE;
    u16 h = f2h_ftz(v);
    float r = v - __half2float(__ushort_as_half(h));
    h8[j] = h;
    l8[j] = f2h_ftz(r);
  }
  size_t o = ((size_t)pn * 512 + (size_t)ks * 64 + lane) * 8;
  st8(xh + o, h8); st8(xl + o, l8);
}

// ------- prologue kernel: packpool (b<128) + packx q0 (128..383) + q1 (384..639)
__global__ __launch_bounds__(512) void k_pre(const float* __restrict__ pool,
                                             const float* __restrict__ pinv,
                                             u16* __restrict__ ah,
                                             u16* __restrict__ al,
                                             u16* __restrict__ ph,
                                             const float* __restrict__ x,
                                             u16* __restrict__ xh,
                                             u16* __restrict__ xl) {
  int b = blockIdx.x;
  if (b < 128) packpool_body(b, pool, pinv, ah, al, ph);
  else if (b < 384) packx_body(b - 128, 0, x, xh, xl);
  else packx_body(b - 384, 1, x, xh, xl);
}

// ---------------- mfma body: sbuf region for (pT, pixT) of one quarter -------
// b encodes pT = b&15, pixT = b>>4. 512 thr / 8 waves, wave owns 1 pm.
// B fragments staged to LDS via global_load_lds, double-buffered 2-phase
// pipeline: stage(ks+1) || compute(ks); one barrier/iter.
__device__ __forceinline__ void mfma_body(int b, int mq,
                                          const u16* __restrict__ ah_,
                                          const u16* __restrict__ al_,
                                          const u16* __restrict__ xh_,
                                          const u16* __restrict__ xl_,
                                          float* __restrict__ sbuf,
                                          u16 (*sB)[2][8][512]) {
  const int t = threadIdx.x, lane = t & 63, w = t >> 6;     // w 0..7
  const int pT = b & 15, pixT = b >> 4;                     // pixT 0..31
  const int pm = pT * 8 + w;
  const int pnBase = mq * 256 + pixT * 8;
  const half8* A8h = (const half8*)ah_;
  const half8* A8l = (const half8*)al_;
  const u16* xsrc[2] = {xh_, xl_};

  floatx4 acc[8];
#pragma unroll
  for (int nt = 0; nt < 8; ++nt) acc[nt] = (floatx4){0.f, 0.f, 0.f, 0.f};

  // prologue: stage slab ks=0 into buffer 0 (16 rows over 8 waves = 2/wave)
#pragma unroll
  for (int q = 0; q < 2; ++q) {
    int id = w * 2 + q;
    int arr = id >> 3, nt = id & 7;
    gl_lds16(xsrc[arr] + ((size_t)(pnBase + nt) * 512 + lane) * 8,
             &sB[0][arr][nt][0]);
  }
  __syncthreads();

#pragma unroll 1
  for (int ks = 0; ks < 8; ++ks) {
    const int cur = ks & 1;
    half8 aH, aL;
    {
      size_t idx = (size_t)pm * 512 + (size_t)ks * 64 + lane;
      aH = A8h[idx]; aL = A8l[idx];
    }
    if (ks < 7) {
#pragma unroll
      for (int q = 0; q < 2; ++q) {
        int id = w * 2 + q;
        int arr = id >> 3, nt = id & 7;
        gl_lds16(xsrc[arr] + ((size_t)(pnBase + nt) * 512 + (ks + 1) * 64 + lane) * 8,
                 &sB[cur ^ 1][arr][nt][0]);
      }
    }
#pragma unroll
    for (int nt = 0; nt < 8; ++nt) {
      half8 bh = *(const half8*)&sB[cur][0][nt][lane * 8];
      half8 bl = *(const half8*)&sB[cur][1][nt][lane * 8];
      floatx4 c = acc[nt];
      c = __builtin_amdgcn_mfma_f32_16x16x32_f16(aH, bh, c, 0, 0, 0);
      c = __builtin_amdgcn_mfma_f32_16x16x32_f16(aH, bl, c, 0, 0, 0);
      c = __builtin_amdgcn_mfma_f32_16x16x32_f16(aL, bh, c, 0, 0, 0);
      acc[nt] = c;
    }
    __syncthreads();   // drains staged loads + protects buffer reuse
  }

  const int qr = lane >> 4, cl = lane & 15;
  const int pix0 = pixT * 128;
  const int pcol = pT * 128 + w * 16;
#pragma unroll
  for (int nt = 0; nt < 8; ++nt) {
    float* dst = sbuf + (size_t)(pix0 + nt * 16 + cl) * P_DIM + pcol + qr * 4;
    *(float4*)dst = make_float4(acc[nt][0], acc[nt][1], acc[nt][2], acc[nt][3]);
  }
}

// ---------------- select body: per-pixel top-102 + renorm + recon -----------
// b = sel block index within quarter; wave wv owns pixel b*8+wv (chunk-local
// sbuf row). value (q, rr) at lane: p = q*256 + lane*4 + rr. (r6 proven form.)
__device__ __forceinline__ void select_body(int b, int sq,
                                            const float* __restrict__ sbuf,
                                            const u16* __restrict__ pool_h,
                                            float* __restrict__ out,
                                            float (*tbuf)[260],
                                            int2 (*kpw)[KPAD]) {
  const int t = threadIdx.x;
  const int lane = t & 63;
  const int wv = t >> 6;
  const int gp0 = sq * QTR_PIX + b * 8;
  const int n = gp0 >> 10;
  const int l0 = gp0 & 1023;
  const float* sp = sbuf + (size_t)(b * 8 + wv) * P_DIM;

  float4 v[8];
#pragma unroll
  for (int q = 0; q < 8; ++q) v[q] = *(const float4*)(sp + q * 256 + lane * 4);

  if (lane < KPAD - KEEP) kpw[wv][KEEP + lane] = make_int2(0, 0);

  // ---- wave max of |s| ----
  float M = 0.f;
#pragma unroll
  for (int q = 0; q < 8; ++q) {
    M = fmaxf(M, fabsf(v[q].x)); M = fmaxf(M, fabsf(v[q].y));
    M = fmaxf(M, fabsf(v[q].z)); M = fmaxf(M, fabsf(v[q].w));
  }
#pragma unroll
  for (int off = 1; off < 64; off <<= 1) M = fmaxf(M, __shfl_xor(M, off));
  const unsigned bitsM = __float_as_uint(M);

  auto countGE = [&](float mf) -> unsigned {
    unsigned cnt = 0;
#pragma unroll
    for (int q = 0; q < 8; ++q) {
      cnt += (unsigned)__popcll(__ballot(fabsf(v[q].x) >= mf));
      cnt += (unsigned)__popcll(__ballot(fabsf(v[q].y) >= mf));
      cnt += (unsigned)__popcll(__ballot(fabsf(v[q].z) >= mf));
      cnt += (unsigned)__popcll(__ballot(fabsf(v[q].w) >= mf));
    }
    return cnt;
  };

  // ---- quad-probe seed: one fused ILP pass over 4 fixed thresholds ----
  const unsigned t1 = (bitsM > (1u << 23)) ? bitsM - (1u << 23) : 1u;
  const unsigned t2 = (bitsM > (2u << 23)) ? bitsM - (2u << 23) : 1u;
  const unsigned t3 = (bitsM > (3u << 23)) ? bitsM - (3u << 23) : 1u;
  const unsigned t4 = (bitsM > (5u << 23)) ? bitsM - (5u << 23) : 1u;
  const float g1 = __uint_as_float(t1), g2 = __uint_as_float(t2);
  const float g3 = __uint_as_float(t3), g4 = __uint_as_float(t4);
  unsigned c1 = 0, c2 = 0, c3 = 0, c4 = 0;
#pragma unroll
  for (int q = 0; q < 8; ++q) {
    const float* f = (const float*)&v[q];
#pragma unroll
    for (int rr = 0; rr < 4; ++rr) {
      float av = fabsf(f[rr]);
      c1 += (unsigned)__popcll(__ballot(av >= g1));
      c2 += (unsigned)__popcll(__ballot(av >= g2));
      c3 += (unsigned)__popcll(__ballot(av >= g3));
      c4 += (unsigned)__popcll(__ballot(av >= g4));
    }
  }

  // invariant: count(>=lo) >= KEEP > count(>=hi). exact: count == KEEP ->
  // probe IS a valid threshold (kept set == the KEEP largest), no ties.
  unsigned lo = 0u, hi = 1u, cl_ = P_DIM, ch_ = 0u;
  bool exact = false;
  if (c1 == (unsigned)KEEP)      { lo = t1; exact = true; }
  else if (c2 == (unsigned)KEEP) { lo = t2; exact = true; }
  else if (c3 == (unsigned)KEEP) { lo = t3; exact = true; }
  else if (c4 == (unsigned)KEEP) { lo = t4; exact = true; }
  else if (c1 > (unsigned)KEEP)  { lo = t1; cl_ = c1; hi = bitsM + 1u; ch_ = 0u; }
  else if (c2 > (unsigned)KEEP)  { lo = t2; cl_ = c2; hi = t1; ch_ = c1; }
  else if (c3 > (unsigned)KEEP)  { lo = t3; cl_ = c3; hi = t2; ch_ = c2; }
  else if (c4 > (unsigned)KEEP)  { lo = t4; cl_ = c4; hi = t3; ch_ = c3; }
  else                           { lo = 0u; cl_ = P_DIM; hi = t4; ch_ = c4; }

  int it = 0;
  while (!exact && hi - lo > 1u) {
    unsigned span = hi - lo;
    unsigned step;
    if ((it++ & 1) == 0) {
      step = (unsigned)((float)span * (float)(cl_ - KEEP) / (float)(cl_ - ch_));
    } else {
      step = span >> 1;
    }
    if (step < 1u) step = 1u;
    else if (step > span - 1u) step = span - 1u;
    unsigned m = lo + step;
    unsigned cnt = countGE(__uint_as_float(m));
    if (cnt == (unsigned)KEEP) { lo = m; exact = true; break; }
    if (cnt > (unsigned)KEEP) { lo = m; cl_ = cnt; } else { hi = m; ch_ = cnt; }
  }
  const float V = __uint_as_float(lo);
  const float Vp = exact ? V : __uint_as_float(lo + 1u);

  unsigned rrem = 0u;
  if (!exact) {
    unsigned gt = countGE(Vp);
    rrem = (unsigned)KEEP - gt;
  }

  unsigned gmask[8], tmask[8];
#pragma unroll
  for (int q = 0; q < 8; ++q) {
    const float* f = (const float*)&v[q];
    unsigned gm = 0, tm = 0;
#pragma unroll
    for (int rr = 0; rr < 4; ++rr) {
      float av = fabsf(f[rr]);
      if (av >= Vp) gm |= (1u << rr);
      else if (av >= V) tm |= (1u << rr);
    }
    gmask[q] = gm; tmask[q] = tm;
  }

  const unsigned long long lowm = (1ull << lane) - 1ull;
  unsigned base = 0, tiebase = 0;
  float Ssum = 0.f;
#pragma unroll
  for (int q = 0; q < 8; ++q) {
    const float* f = (const float*)&v[q];
    unsigned km = gmask[q];
    if (rrem != 0u) {        // wave-uniform: tie handling only when needed
      unsigned teq = 0, myeqb = 0;
#pragma unroll
      for (int rr = 0; rr < 4; ++rr) {
        unsigned long long beq = __ballot((tmask[q] >> rr) & 1u);
        teq += (unsigned)__popcll(beq);
        myeqb += (unsigned)__popcll(beq & lowm);
      }
      unsigned cum = 0;
#pragma unroll
      for (int rr = 0; rr < 4; ++rr) {
        if ((tmask[q] >> rr) & 1u) {
          if (tiebase + myeqb + cum < rrem) km |= (1u << rr);
          ++cum;
        }
      }
      tiebase += teq;
    }
    unsigned long long bk[4];
    unsigned tot = 0, myb = 0;
#pragma unroll
    for (int rr = 0; rr < 4; ++rr) {
      bk[rr] = __ballot((km >> rr) & 1u);
      tot += (unsigned)__popcll(bk[rr]);
      myb += (unsigned)__popcll(bk[rr] & lowm);
    }
    {
      unsigned cum = 0;
#pragma unroll
      for (int rr = 0; rr < 4; ++rr) {
        if ((km >> rr) & 1u) {
          unsigned pos = base + myb + cum;
          // PRE-MULTIPLIED byte offset into pool_h (p * 256 u16 * 2B)
          kpw[wv][pos] = make_int2((q * 256 + lane * 4 + rr) << 9,
                                   __float_as_int(f[rr]));
          Ssum += f[rr];
          ++cum;
        }
      }
    }
    base += tot;
  }

#pragma unroll
  for (int off = 1; off < 64; off <<= 1) Ssum += __shfl_xor(Ssum, off);
  const float invS = 1.0f / Ssum;

  __builtin_amdgcn_wave_barrier();

  // ---- recon: out_c = invS * sum_kept s_p * pool_h[p][c], c = 4*lane+j.
  //      fp16 rows (512 B/wave); ping-pong A/B groups of 4, 1-group-ahead
  //      prefetch, v_fma_mix_f32 mixed FMA (r6 proven structure). ----
  float a0 = 0.f, a1 = 0.f, a2 = 0.f, a3 = 0.f;
  const char* pb = (const char*)(pool_h + 4 * lane);
  int2 eA[4], eB[4];
  uint2 rA[4], rB[4];

  auto PROC = [&](const int2* e, const uint2* r) {
#pragma unroll
    for (int j = 0; j < 4; ++j) {
      float w2 = __int_as_float(e[j].y);
      unsigned rx = r[j].x, ry = r[j].y;
      asm volatile("v_fma_mix_f32 %0, %1, %2, %0 op_sel:[0,0,0] op_sel_hi:[0,1,0]"
                   : "+v"(a0) : "v"(w2), "v"(rx));
      asm volatile("v_fma_mix_f32 %0, %1, %2, %0 op_sel:[0,1,0] op_sel_hi:[0,1,0]"
                   : "+v"(a1) : "v"(w2), "v"(rx));
      asm volatile("v_fma_mix_f32 %0, %1, %2, %0 op_sel:[0,0,0] op_sel_hi:[0,1,0]"
                   : "+v"(a2) : "v"(w2), "v"(ry));
      asm volatile("v_fma_mix_f32 %0, %1, %2, %0 op_sel:[0,1,0] op_sel_hi:[0,1,0]"
                   : "+v"(a3) : "v"(w2), "v"(ry));
    }
  };

#pragma unroll
  for (int j = 0; j < 4; ++j) eA[j] = kpw[wv][j];
#pragma unroll
  for (int j = 0; j < 4; ++j) rA[j] = *(const uint2*)(pb + (unsigned)eA[j].x);
  // KPAD = 104 = 13 * 8
#pragma unroll 1
  for (int k = 0; k < KPAD; k += 8) {
    const int kb = k + 4;                       // < KPAD always
#pragma unroll
    for (int j = 0; j < 4; ++j) eB[j] = kpw[wv][kb + j];
#pragma unroll
    for (int j = 0; j < 4; ++j) rB[j] = *(const uint2*)(pb + (unsigned)eB[j].x);
    PROC(eA, rA);
    const int ka = (k + 8 < KPAD) ? k + 8 : 0;  // dummy prefetch on last iter
#pragma unroll
    for (int j = 0; j < 4; ++j) eA[j] = kpw[wv][ka + j];
#pragma unroll
    for (int j = 0; j < 4; ++j) rA[j] = *(const uint2*)(pb + (unsigned)eA[j].x);
    PROC(eB, rB);
  }
  a0 *= invS; a1 *= invS; a2 *= invS; a3 *= invS;

  *(float4*)&tbuf[wv][4 * lane] = make_float4(a0, a1, a2, a3);
  __syncthreads();

  {
    int c = t >> 1, lq = t & 1;
    float4 o = make_float4(tbuf[4 * lq + 0][c], tbuf[4 * lq + 1][c],
                           tbuf[4 * lq + 2][c], tbuf[4 * lq + 3][c]);
    *(float4*)(out + ((size_t)(n * C_DIM + c)) * L_DIM + l0 + 4 * lq) = o;
  }
}

// ---------------- persistent dataflow pipeline kernel ------------------------
// 1024 blocks = 32 units x (16 M-blocks + 16 S-blocks). Unit g owns pixels
// [128g, 128g+128) of every quarter; all dependencies are intra-unit flags:
//   M phase q: [q>=2: wait rd_cnt[q-2][g]==16 (slot free) and
//              pack_cnt[q][g]==8 (own unit packed B in phase q-2)]
//              mfma -> signal mf_cnt[q][g]; if q<2 && pT<8: pack pn 8g+pT
//              for quarter q+2 -> signal pack_cnt[q+2][g].
//   S phase q: wait mf_cnt[q][g]==16 -> select -> signal rd_cnt[q][g].
// M-blocks precede S-blocks per unit and never wait on other units =>
// deadlock-free at any residency >= 1 unit (32 blocks). Launch bounds force
// 4 blocks/CU capacity (LDS 32 KB, 512 thr, VGPR <= 128) => all co-resident.
__global__ __launch_bounds__(512, 4) void k_pipe(const u16* __restrict__ ah_,
                                                 const u16* __restrict__ al_,
                                                 u16* __restrict__ xh_,
                                                 u16* __restrict__ xl_,
                                                 const u16* __restrict__ ph,
                                                 const float* __restrict__ x,
                                                 float* __restrict__ sbuf0,
                                                 float* __restrict__ sbuf1,
                                                 float* __restrict__ out,
                                                 int* __restrict__ flags) {
  __shared__ __align__(16) SMem sm;
  const int b = blockIdx.x;
  const int g = b >> 5;        // unit 0..31
  const int r = b & 31;        // 0..15 = M(pT=r), 16..31 = S(j=r-16)
  int* pack_cnt = flags + F_PACK;
  int* mf_cnt = flags + F_MF;
  int* rd_cnt = flags + F_RD;

  if (r < 16) {
    // ---- M role ----
    const int mb = r + 16 * g;                 // pT | pixT<<4
#pragma unroll 1
    for (int q = 0; q < 4; ++q) {
      if (q >= 2) {
        wait_flag(&rd_cnt[(q - 2) * 32 + g], 16);   // sbuf slot free
        wait_flag(&pack_cnt[q * 32 + g], 8);        // B rows packed
      }
      mfma_body(mb, q, ah_, al_, xh_, xl_, (q & 1) ? sbuf1 : sbuf0, sm.sB);
      __syncthreads();                         // drain sbuf stores (vmcnt)
      signal_flag(&mf_cnt[q * 32 + g]);        // release: wbl2 + atomic add
      if (q < 2 && r < 8) {
        packx_body(8 * g + r, q + 2, x, xh_, xl_);
        __syncthreads();                       // drain pack stores
        signal_flag(&pack_cnt[(q + 2) * 32 + g]);
      }
    }
  } else {
    // ---- S role ----
    const int sb = g * 16 + (r - 16);
#pragma unroll 1
    for (int q = 0; q < 4; ++q) {
      wait_flag(&mf_cnt[q * 32 + g], 16);      // acquire: region written
      select_body(sb, q, (q & 1) ? sbuf1 : sbuf0, ph, out,
                  sm.sel.tbuf, sm.sel.kpw);
      __syncthreads();                         // all reads complete
      signal_flag(&rd_cnt[q * 32 + g]);        // slot release
    }
  }
}

// ---------------- launch ----------------
// d_ws layout (~83 MB):
//   sbuf0 33,554,432 | sbuf1 33,554,432 | xh/xl 2 x 8,388,608
//   ah/al 2 x 1,048,576 | pool_h 1,048,576 | pinv 8,192 | flags 1,536
extern "C" void kernel_launch(void* const* d_in, const int* in_sizes, int n_in,
                              void* d_out, int out_size, void* d_ws, size_t ws_size,
                              hipStream_t stream) {
  const float* x = (const float*)d_in[0];
  const float* pool = (const float*)d_in[1];
  float* out = (float*)d_out;
  char* wsb = (char*)d_ws;
  float* sbuf0 = (float*)wsb;
  float* sbuf1 = (float*)(wsb + 33554432);
  u16* xh = (u16*)(wsb + 67108864);
  u16* xl = xh + 4194304;
  u16* ah = xl + 4194304;
  u16* al = ah + 524288;
  u16* ph = al + 524288;
  float* pinv = (float*)(ph + 524288);
  int* flags = (int*)(pinv + 2048);

  k_pinv<<<P_DIM / 256, 256, 0, stream>>>(pool, pinv, flags);
  k_pre<<<640, 512, 0, stream>>>(pool, pinv, ah, al, ph, x, xh, xl);
  k_pipe<<<1024, 512, 0, stream>>>(ah, al, xh, xl, ph, x, sbuf0, sbuf1, out, flags);
}

// Round 13
// 234.873 us; speedup vs baseline: 1.9513x; 1.9513x over previous
//
#include <hip/hip_runtime.h>
#include <hip/hip_fp16.h>

typedef unsigned short u16;
typedef _Float16 half8 __attribute__((ext_vector_type(8)));
typedef float floatx4 __attribute__((ext_vector_type(4)));

#define C_DIM 256
#define P_DIM 2048
#define L_DIM 1024
#define N_DIM 16
#define KEEP 102
#define KPAD 104
#define QTR_PIX 4096    // pixels per quarter-pass
#define SCALE 256.0f    // 2^8 input pre-scale; both operands scaled -> acc at 2^16.
                        // Downstream is scale-invariant (topk order + w/Sum(w)).

__device__ __forceinline__ void st8(u16* dst, const u16* s) {
  uint4 u;
  u.x = (unsigned)s[0] | ((unsigned)s[1] << 16);
  u.y = (unsigned)s[2] | ((unsigned)s[3] << 16);
  u.z = (unsigned)s[4] | ((unsigned)s[5] << 16);
  u.w = (unsigned)s[6] | ((unsigned)s[7] << 16);
  *(uint4*)dst = u;
}

// fp32 -> fp16 with flush-to-zero of subnormal results (MFMA denormal guard).
__device__ __forceinline__ u16 f2h_ftz(float v) {
  if (fabsf(v) < 6.103515625e-5f) return 0;
  return __half_as_ushort(__float2half(v));
}

// async global->LDS, 16B per lane. LDS dest is wave-uniform base + lane*16.
__device__ __forceinline__ void gl_lds16(const u16* g, u16* l) {
  __builtin_amdgcn_global_load_lds(
      (const __attribute__((address_space(1))) unsigned int*)g,
      (__attribute__((address_space(3))) unsigned int*)l, 16, 0, 0);
}

// shared-memory overlay: mfma role needs 32 KB staging, select role ~15 KB
union SMem {
  u16 sB[2][2][8][512];                               // 32768 B
  struct {
    float tbuf[8][260];                               // 8320 B
    int2  kpw[8][KPAD];                               // 6656 B (byte-off, weight)
  } sel;
};

// ------- packpool role: pool*pinv*2^8 into MFMA-A frag order, fp16 hi/lo,
//         plus raw fp16 pool copy for the recon gather. 128 blocks x 512 thr.
//         pinv computed INLINE (block covers all 256 cols of its 16 p rows):
//         per-thread partial sum of squares -> shfl_xor(16,32) -> 8x16 LDS
//         cross-wave reduce. Deletes the k_pinv dispatch + boundary. -------
// frag element (pm, ks, lane, j): p = pm*16 + (lane&15), c = ks*32 + (lane>>4)*8 + j
__device__ __forceinline__ void packpool_body(int b,
                                              const float* __restrict__ pool,
                                              u16* __restrict__ ah,
                                              u16* __restrict__ al,
                                              u16* __restrict__ ph) {
  __shared__ float ppart[8][16];
  int tid = b * 512 + threadIdx.x;              // 65536 = 128*8*64
  int lane = tid & 63;
  int ks = (tid >> 6) & 7;
  int w = threadIdx.x >> 6;
  int pm = tid >> 9;                            // == b (one pm per block)
  int p = pm * 16 + (lane & 15);
  int c0 = ks * 32 + ((lane >> 4) << 3);
  const float* src = pool + (size_t)p * C_DIM + c0;

  float raw[8];
  float part = 0.f;
#pragma unroll
  for (int j = 0; j < 8; ++j) {
    raw[j] = src[j];
    part += raw[j] * raw[j];
  }
  // reduce over the 4 lanes sharing lane&15 within the wave
  part += __shfl_xor(part, 16);
  part += __shfl_xor(part, 32);
  if (lane < 16) ppart[w][lane] = part;
  __syncthreads();
  float s = 0.f;
#pragma unroll
  for (int w2 = 0; w2 < 8; ++w2) s += ppart[w2][lane & 15];
  float sc = (1.0f / sqrtf(s)) * SCALE;

  u16 h8[8], l8[8], p8[8];
#pragma unroll
  for (int j = 0; j < 8; ++j) {
    float rawj = raw[j];
    p8[j] = __half_as_ushort(__float2half(rawj));
    float v = rawj * sc;
    u16 h = f2h_ftz(v);
    float r = v - __half2float(__ushort_as_half(h));  // exact (Sterbenz range)
    h8[j] = h;
    l8[j] = f2h_ftz(r);
  }
  size_t o = (size_t)tid * 8;
  st8(ah + o, h8); st8(al + o, l8);
  st8(ph + (size_t)p * C_DIM + c0, p8);
}

// ------- packx role: x*2^8 into MFMA-B frag order, fp16 hi/lo split ---------
// One quarter = 256 blocks x 512 threads; block pb packs pn = pq*256 + pb.
// frag element (pn, ks, lane, j): pix = pn*16 + (lane&15), c = ks*32 + (lane>>4)*8 + j
__device__ __forceinline__ void packx_body(int pb, int pq,
                                           const float* __restrict__ x,
                                           u16* __restrict__ xh,
                                           u16* __restrict__ xl) {
  int t = threadIdx.x;
  int lane = t & 63;
  int ks = (t >> 6) & 7;
  int pn = pq * 256 + pb;
  int pix = pn * 16 + (lane & 15);
  int n = pix >> 10, l = pix & 1023;
  int c0 = ks * 32 + ((lane >> 4) << 3);
  const float* src = x + ((size_t)(n * C_DIM + c0)) * L_DIM + l;
  u16 h8[8], l8[8];
#pragma unroll
  for (int j = 0; j < 8; ++j) {
    float v = src[(size_t)j * L_DIM] * SCALE;
    u16 h = f2h_ftz(v);
    float r = v - __half2float(__ushort_as_half(h));
    h8[j] = h;
    l8[j] = f2h_ftz(r);
  }
  size_t o = ((size_t)pn * 512 + (size_t)ks * 64 + lane) * 8;
  st8(xh + o, h8); st8(xl + o, l8);
}

// ------- prologue kernel: packpool (b<128) + packx quarter 0 (b>=128) -------
__global__ __launch_bounds__(512) void k_pre(const float* __restrict__ pool,
                                             u16* __restrict__ ah,
                                             u16* __restrict__ al,
                                             u16* __restrict__ ph,
                                             const float* __restrict__ x,
                                             u16* __restrict__ xh,
                                             u16* __restrict__ xl) {
  int b = blockIdx.x;
  if (b < 128) packpool_body(b, pool, ah, al, ph);
  else packx_body(b - 128, 0, x, xh, xl);
}

// ---------------- mfma role: sbuf[pixLocal][p], one quarter (4096 pix) -------
// 512 blocks = pT(16) x pixT(32); 512 thr / 8 waves, wave owns 1 pm (16 P rows).
// B fragments staged to LDS via global_load_lds, double-buffered 2-phase
// pipeline: stage(ks+1) || compute(ks); one barrier/iter.
__device__ __forceinline__ void mfma_body(int b, int mq,
                                          const u16* __restrict__ ah_,
                                          const u16* __restrict__ al_,
                                          const u16* __restrict__ xh_,
                                          const u16* __restrict__ xl_,
                                          float* __restrict__ sbuf,
                                          u16 (*sB)[2][8][512]) {
  const int t = threadIdx.x, lane = t & 63, w = t >> 6;     // w 0..7
  const int pT = b & 15, pixT = b >> 4;                     // pixT 0..31
  const int pm = pT * 8 + w;
  const int pnBase = mq * 256 + pixT * 8;
  const half8* A8h = (const half8*)ah_;
  const half8* A8l = (const half8*)al_;
  const u16* xsrc[2] = {xh_, xl_};

  floatx4 acc[8];
#pragma unroll
  for (int nt = 0; nt < 8; ++nt) acc[nt] = (floatx4){0.f, 0.f, 0.f, 0.f};

  // prologue: stage slab ks=0 into buffer 0 (16 rows over 8 waves = 2/wave)
#pragma unroll
  for (int q = 0; q < 2; ++q) {
    int id = w * 2 + q;
    int arr = id >> 3, nt = id & 7;
    gl_lds16(xsrc[arr] + ((size_t)(pnBase + nt) * 512 + lane) * 8,
             &sB[0][arr][nt][0]);
  }
  __syncthreads();

#pragma unroll 1
  for (int ks = 0; ks < 8; ++ks) {
    const int cur = ks & 1;
    half8 aH, aL;
    {
      size_t idx = (size_t)pm * 512 + (size_t)ks * 64 + lane;
      aH = A8h[idx]; aL = A8l[idx];
    }
    if (ks < 7) {
#pragma unroll
      for (int q = 0; q < 2; ++q) {
        int id = w * 2 + q;
        int arr = id >> 3, nt = id & 7;
        gl_lds16(xsrc[arr] + ((size_t)(pnBase + nt) * 512 + (ks + 1) * 64 + lane) * 8,
                 &sB[cur ^ 1][arr][nt][0]);
      }
    }
#pragma unroll
    for (int nt = 0; nt < 8; ++nt) {
      half8 bh = *(const half8*)&sB[cur][0][nt][lane * 8];
      half8 bl = *(const half8*)&sB[cur][1][nt][lane * 8];
      floatx4 c = acc[nt];
      c = __builtin_amdgcn_mfma_f32_16x16x32_f16(aH, bh, c, 0, 0, 0);
      c = __builtin_amdgcn_mfma_f32_16x16x32_f16(aH, bl, c, 0, 0, 0);
      c = __builtin_amdgcn_mfma_f32_16x16x32_f16(aL, bh, c, 0, 0, 0);
      acc[nt] = c;
    }
    __syncthreads();   // drains staged loads + protects buffer reuse
  }

  const int qr = lane >> 4, cl = lane & 15;
  const int pix0 = pixT * 128;
  const int pcol = pT * 128 + w * 16;
#pragma unroll
  for (int nt = 0; nt < 8; ++nt) {
    float* dst = sbuf + (size_t)(pix0 + nt * 16 + cl) * P_DIM + pcol + qr * 4;
    *(float4*)dst = make_float4(acc[nt][0], acc[nt][1], acc[nt][2], acc[nt][3]);
  }
}

// ---------------- select role: per-pixel top-102 + renorm + recon -----------
// One quarter. 512 blocks; 512 threads = 8 waves; wave wv owns one pixel.
// value (q, rr) at lane: p = q*256 + lane*4 + rr
__device__ __forceinline__ void select_body(int b, int sq,
                                            const float* __restrict__ sbuf,
                                            const u16* __restrict__ pool_h,
                                            float* __restrict__ out,
                                            float (*tbuf)[260],
                                            int2 (*kpw)[KPAD]) {
  const int t = threadIdx.x;
  const int lane = t & 63;
  const int wv = t >> 6;
  const int gp0 = sq * QTR_PIX + b * 8;
  const int n = gp0 >> 10;
  const int l0 = gp0 & 1023;
  const float* sp = sbuf + (size_t)(b * 8 + wv) * P_DIM;

  float4 v[8];
#pragma unroll
  for (int q = 0; q < 8; ++q) v[q] = *(const float4*)(sp + q * 256 + lane * 4);

  if (lane < KPAD - KEEP) kpw[wv][KEEP + lane] = make_int2(0, 0);

  // ---- wave max of |s| ----
  float M = 0.f;
#pragma unroll
  for (int q = 0; q < 8; ++q) {
    M = fmaxf(M, fabsf(v[q].x)); M = fmaxf(M, fabsf(v[q].y));
    M = fmaxf(M, fabsf(v[q].z)); M = fmaxf(M, fabsf(v[q].w));
  }
#pragma unroll
  for (int off = 1; off < 64; off <<= 1) M = fmaxf(M, __shfl_xor(M, off));
  const unsigned bitsM = __float_as_uint(M);

  auto countGE = [&](float mf) -> unsigned {
    unsigned cnt = 0;
#pragma unroll
    for (int q = 0; q < 8; ++q) {
      cnt += (unsigned)__popcll(__ballot(fabsf(v[q].x) >= mf));
      cnt += (unsigned)__popcll(__ballot(fabsf(v[q].y) >= mf));
      cnt += (unsigned)__popcll(__ballot(fabsf(v[q].z) >= mf));
      cnt += (unsigned)__popcll(__ballot(fabsf(v[q].w) >= mf));
    }
    return cnt;
  };

  // ---- quad-probe seed: one fused ILP pass over 4 fixed thresholds
  //      {M/2, M/4, M/8, M/32} replaces ~4 serial bracketing passes. ----
  const unsigned t1 = (bitsM > (1u << 23)) ? bitsM - (1u << 23) : 1u;
  const unsigned t2 = (bitsM > (2u << 23)) ? bitsM - (2u << 23) : 1u;
  const unsigned t3 = (bitsM > (3u << 23)) ? bitsM - (3u << 23) : 1u;
  const unsigned t4 = (bitsM > (5u << 23)) ? bitsM - (5u << 23) : 1u;
  const float g1 = __uint_as_float(t1), g2 = __uint_as_float(t2);
  const float g3 = __uint_as_float(t3), g4 = __uint_as_float(t4);
  unsigned c1 = 0, c2 = 0, c3 = 0, c4 = 0;
#pragma unroll
  for (int q = 0; q < 8; ++q) {
    const float* f = (const float*)&v[q];
#pragma unroll
    for (int rr = 0; rr < 4; ++rr) {
      float av = fabsf(f[rr]);
      c1 += (unsigned)__popcll(__ballot(av >= g1));
      c2 += (unsigned)__popcll(__ballot(av >= g2));
      c3 += (unsigned)__popcll(__ballot(av >= g3));
      c4 += (unsigned)__popcll(__ballot(av >= g4));
    }
  }

  // invariant: count(>=lo) >= KEEP > count(>=hi). exact: count == KEEP ->
  // probe IS a valid threshold (kept set == the KEEP largest), no ties.
  unsigned lo = 0u, hi = 1u, cl_ = P_DIM, ch_ = 0u;
  bool exact = false;
  if (c1 == (unsigned)KEEP)      { lo = t1; exact = true; }
  else if (c2 == (unsigned)KEEP) { lo = t2; exact = true; }
  else if (c3 == (unsigned)KEEP) { lo = t3; exact = true; }
  else if (c4 == (unsigned)KEEP) { lo = t4; exact = true; }
  else if (c1 > (unsigned)KEEP)  { lo = t1; cl_ = c1; hi = bitsM + 1u; ch_ = 0u; }
  else if (c2 > (unsigned)KEEP)  { lo = t2; cl_ = c2; hi = t1; ch_ = c1; }
  else if (c3 > (unsigned)KEEP)  { lo = t3; cl_ = c3; hi = t2; ch_ = c2; }
  else if (c4 > (unsigned)KEEP)  { lo = t4; cl_ = c4; hi = t3; ch_ = c3; }
  else                           { lo = 0u; cl_ = P_DIM; hi = t4; ch_ = c4; }

  int it = 0;
  while (!exact && hi - lo > 1u) {
    unsigned span = hi - lo;
    unsigned step;
    if ((it++ & 1) == 0) {
      step = (unsigned)((float)span * (float)(cl_ - KEEP) / (float)(cl_ - ch_));
    } else {
      step = span >> 1;
    }
    if (step < 1u) step = 1u;
    else if (step > span - 1u) step = span - 1u;
    unsigned m = lo + step;
    unsigned cnt = countGE(__uint_as_float(m));
    if (cnt == (unsigned)KEEP) { lo = m; exact = true; break; }
    if (cnt > (unsigned)KEEP) { lo = m; cl_ = cnt; } else { hi = m; ch_ = cnt; }
  }
  const float V = __uint_as_float(lo);
  const float Vp = exact ? V : __uint_as_float(lo + 1u);

  unsigned rrem = 0u;
  if (!exact) {
    unsigned gt = countGE(Vp);
    rrem = (unsigned)KEEP - gt;
  }

  unsigned gmask[8], tmask[8];
#pragma unroll
  for (int q = 0; q < 8; ++q) {
    const float* f = (const float*)&v[q];
    unsigned gm = 0, tm = 0;
#pragma unroll
    for (int rr = 0; rr < 4; ++rr) {
      float av = fabsf(f[rr]);
      if (av >= Vp) gm |= (1u << rr);
      else if (av >= V) tm |= (1u << rr);
    }
    gmask[q] = gm; tmask[q] = tm;
  }

  const unsigned long long lowm = (1ull << lane) - 1ull;
  unsigned base = 0, tiebase = 0;
  float Ssum = 0.f;
#pragma unroll
  for (int q = 0; q < 8; ++q) {
    const float* f = (const float*)&v[q];
    unsigned km = gmask[q];
    if (rrem != 0u) {        // wave-uniform: tie handling only when needed
      unsigned teq = 0, myeqb = 0;
#pragma unroll
      for (int rr = 0; rr < 4; ++rr) {
        unsigned long long beq = __ballot((tmask[q] >> rr) & 1u);
        teq += (unsigned)__popcll(beq);
        myeqb += (unsigned)__popcll(beq & lowm);
      }
      unsigned cum = 0;
#pragma unroll
      for (int rr = 0; rr < 4; ++rr) {
        if ((tmask[q] >> rr) & 1u) {
          if (tiebase + myeqb + cum < rrem) km |= (1u << rr);
          ++cum;
        }
      }
      tiebase += teq;
    }
    unsigned long long bk[4];
    unsigned tot = 0, myb = 0;
#pragma unroll
    for (int rr = 0; rr < 4; ++rr) {
      bk[rr] = __ballot((km >> rr) & 1u);
      tot += (unsigned)__popcll(bk[rr]);
      myb += (unsigned)__popcll(bk[rr] & lowm);
    }
    {
      unsigned cum = 0;
#pragma unroll
      for (int rr = 0; rr < 4; ++rr) {
        if ((km >> rr) & 1u) {
          unsigned pos = base + myb + cum;
          // PRE-MULTIPLIED byte offset into pool_h (p * 256 u16 * 2B)
          kpw[wv][pos] = make_int2((q * 256 + lane * 4 + rr) << 9,
                                   __float_as_int(f[rr]));
          Ssum += f[rr];
          ++cum;
        }
      }
    }
    base += tot;
  }

#pragma unroll
  for (int off = 1; off < 64; off <<= 1) Ssum += __shfl_xor(Ssum, off);
  const float invS = 1.0f / Ssum;

  __builtin_amdgcn_wave_barrier();

  // ---- recon: out_c = invS * sum_kept s_p * pool_h[p][c], c = 4*lane+j.
  //      fp16 rows (512 B/wave); ping-pong A/B groups of 4, 1-group-ahead
  //      prefetch, v_fma_mix_f32 mixed FMA (r6 proven structure). ----
  float a0 = 0.f, a1 = 0.f, a2 = 0.f, a3 = 0.f;
  const char* pb = (const char*)(pool_h + 4 * lane);
  int2 eA[4], eB[4];
  uint2 rA[4], rB[4];

  auto PROC = [&](const int2* e, const uint2* r) {
#pragma unroll
    for (int j = 0; j < 4; ++j) {
      float w2 = __int_as_float(e[j].y);
      unsigned rx = r[j].x, ry = r[j].y;
      asm volatile("v_fma_mix_f32 %0, %1, %2, %0 op_sel:[0,0,0] op_sel_hi:[0,1,0]"
                   : "+v"(a0) : "v"(w2), "v"(rx));
      asm volatile("v_fma_mix_f32 %0, %1, %2, %0 op_sel:[0,1,0] op_sel_hi:[0,1,0]"
                   : "+v"(a1) : "v"(w2), "v"(rx));
      asm volatile("v_fma_mix_f32 %0, %1, %2, %0 op_sel:[0,0,0] op_sel_hi:[0,1,0]"
                   : "+v"(a2) : "v"(w2), "v"(ry));
      asm volatile("v_fma_mix_f32 %0, %1, %2, %0 op_sel:[0,1,0] op_sel_hi:[0,1,0]"
                   : "+v"(a3) : "v"(w2), "v"(ry));
    }
  };

#pragma unroll
  for (int j = 0; j < 4; ++j) eA[j] = kpw[wv][j];
#pragma unroll
  for (int j = 0; j < 4; ++j) rA[j] = *(const uint2*)(pb + (unsigned)eA[j].x);
  // KPAD = 104 = 13 * 8
#pragma unroll 1
  for (int k = 0; k < KPAD; k += 8) {
    const int kb = k + 4;                       // < KPAD always
#pragma unroll
    for (int j = 0; j < 4; ++j) eB[j] = kpw[wv][kb + j];
#pragma unroll
    for (int j = 0; j < 4; ++j) rB[j] = *(const uint2*)(pb + (unsigned)eB[j].x);
    PROC(eA, rA);
    const int ka = (k + 8 < KPAD) ? k + 8 : 0;  // dummy prefetch on last iter
#pragma unroll
    for (int j = 0; j < 4; ++j) eA[j] = kpw[wv][ka + j];
#pragma unroll
    for (int j = 0; j < 4; ++j) rA[j] = *(const uint2*)(pb + (unsigned)eA[j].x);
    PROC(eB, rB);
  }
  a0 *= invS; a1 *= invS; a2 *= invS; a3 *= invS;

  *(float4*)&tbuf[wv][4 * lane] = make_float4(a0, a1, a2, a3);
  __syncthreads();

  {
    int c = t >> 1, lq = t & 1;
    float4 o = make_float4(tbuf[4 * lq + 0][c], tbuf[4 * lq + 1][c],
                           tbuf[4 * lq + 2][c], tbuf[4 * lq + 3][c]);
    *(float4*)(out + ((size_t)(n * C_DIM + c)) * L_DIM + l0 + 4 * lq) = o;
  }
}

// ---------------- fused pipeline kernel --------------------------------------
// Block roles (in grid order): select(sq) [512] | packx(pq) [256] | mfma(mq) [512].
// sbuf slot = quarter & 1; launch order guarantees mfma(q) precedes select(q);
// packx(q) completes one dispatch before mfma(q) consumes it.
__global__ __launch_bounds__(512, 4) void k_main(const u16* __restrict__ ah_,
                                                 const u16* __restrict__ al_,
                                                 const u16* __restrict__ xh_,
                                                 const u16* __restrict__ xl_,
                                                 const u16* __restrict__ ph,
                                                 const float* __restrict__ x,
                                                 float* __restrict__ sbuf0,
                                                 float* __restrict__ sbuf1,
                                                 float* __restrict__ out,
                                                 int mq, int sq, int pq) {
  __shared__ __align__(16) SMem sm;
  const int b = blockIdx.x;
  const int nsel = (sq >= 0) ? 512 : 0;
  const int npk = (pq >= 0) ? 256 : 0;
  if (b < nsel) {
    select_body(b, sq, (sq & 1) ? sbuf1 : sbuf0, ph, out,
                sm.sel.tbuf, sm.sel.kpw);
  } else if (b < nsel + npk) {
    packx_body(b - nsel, pq, x, (u16*)xh_, (u16*)xl_);
  } else {
    mfma_body(b - nsel - npk, mq, ah_, al_, xh_, xl_, (mq & 1) ? sbuf1 : sbuf0, sm.sB);
  }
}

// ---------------- launch ----------------
// d_ws layout (~83 MB):
//   sbuf0 33,554,432 | sbuf1 33,554,432 | xh/xl 2 x 8,388,608
//   ah/al 2 x 1,048,576 | pool_h 1,048,576
extern "C" void kernel_launch(void* const* d_in, const int* in_sizes, int n_in,
                              void* d_out, int out_size, void* d_ws, size_t ws_size,
                              hipStream_t stream) {
  const float* x = (const float*)d_in[0];
  const float* pool = (const float*)d_in[1];
  float* out = (float*)d_out;
  char* wsb = (char*)d_ws;
  float* sbuf0 = (float*)wsb;
  float* sbuf1 = (float*)(wsb + 33554432);
  u16* xh = (u16*)(wsb + 67108864);
  u16* xl = xh + 4194304;
  u16* ah = xl + 4194304;
  u16* al = ah + 524288;
  u16* ph = al + 524288;

  k_pre<<<384, 512, 0, stream>>>(pool, ah, al, ph, x, xh, xl);

  k_main<<<768, 512, 0, stream>>>(ah, al, xh, xl, ph, x, sbuf0, sbuf1, out, 0, -1, 1);
  k_main<<<1280, 512, 0, stream>>>(ah, al, xh, xl, ph, x, sbuf0, sbuf1, out, 1, 0, 2);
  k_main<<<1280, 512, 0, stream>>>(ah, al, xh, xl, ph, x, sbuf0, sbuf1, out, 2, 1, 3);
  k_main<<<1024, 512, 0, stream>>>(ah, al, xh, xl, ph, x, sbuf0, sbuf1, out, 3, 2, -1);
  k_main<<<512, 512, 0, stream>>>(ah, al, xh, xl, ph, x, sbuf0, sbuf1, out, -1, 3, -1);
}